// Round 11
// baseline (1424.935 us; speedup 1.0000x reference)
//
#include <hip/hip_runtime.h>
#include <cstddef>

typedef unsigned short u16;
typedef unsigned int u32;
typedef __attribute__((ext_vector_type(8))) short short8;
typedef __attribute__((ext_vector_type(4))) float f32x4;
typedef __attribute__((ext_vector_type(4))) u32 u32x4;
typedef __attribute__((ext_vector_type(2))) u32 u32x2;

__device__ inline u16 f2bf(float x) {
  union { float f; u32 u; } v; v.f = x;
  u32 r = v.u + 0x7fffu + ((v.u >> 16) & 1u);
  return (u16)(r >> 16);
}
__device__ inline int swz_of(int pix) {
  return (((pix >> 5) & 1) << 2) ^ (pix & 7);
}
__device__ inline int slot4(int e, int pix) {
  return (e ^ (pix & 3)) | ((((pix >> 2) ^ (pix >> 5)) & 1) << 2);
}

// ---------------- weight packing (MFMA A-fragment order, bf16) ----------------
__global__ void k_pack1(const float* __restrict__ w, u16* __restrict__ wpk) {
  int i = blockIdx.x * 256 + threadIdx.x;  // 81*16*512
  if (i >= 663552) return;
  int j = i & 7, l = (i >> 3) & 63, ot = (i >> 9) & 15, kk = i >> 13;
  int kq = kk / 9, ks = kk % 9;
  int ic = ks * 32 + (l >> 4) * 8 + j;
  int oc = ot * 16 + (l & 15);
  float v = (ic < 259) ? w[(oc * 259 + ic) * 9 + kq] : 0.f;
  wpk[i] = f2bf(v);
}
__global__ void k_pack3(const float* __restrict__ w, u16* __restrict__ wpk) {
  int i = blockIdx.x * 256 + threadIdx.x;  // 3*72*16*512
  if (i >= 1769472) return;
  int j = i & 7, l = (i >> 3) & 63, ot = (i >> 9) & 15, kk2 = i >> 13;
  int ll = kk2 / 72, kk = kk2 % 72;
  int kq = kk / 8, ks = kk % 8;
  int ic = ks * 32 + (l >> 4) * 8 + j;
  int oc = ot * 16 + (l & 15);
  wpk[i] = f2bf(w[((ll * 256 + oc) * 256 + ic) * 9 + kq]);
}
__global__ void k_packd(const float* __restrict__ w, u16* __restrict__ wpk) {
  int i = blockIdx.x * 256 + threadIdx.x;  // 32*16*512
  if (i >= 262144) return;
  int j = i & 7, l = (i >> 3) & 63, ot = (i >> 9) & 15, kk = i >> 13;
  int kl = kk / 8, ks = kk % 8;
  int ic = ks * 32 + (l >> 4) * 8 + j;
  int oc = ot * 16 + (l & 15);
  wpk[i] = f2bf(w[(ic * 256 + oc) * 4 + kl]);
}
__global__ void k_tw_conv2(const float* __restrict__ w, float* __restrict__ wt) {
  int i = blockIdx.x * 256 + threadIdx.x;
  if (i >= 256 * 256) return;
  int oc = i & 255, ic = i >> 8;
  wt[i] = w[oc * 256 + ic];
}

// ---------------- zero halos of NHWC-padded bf16 activation buffers ----------
template <int CH>
__global__ void k_halo(u16* __restrict__ X) {
  int i = blockIdx.x * 256 + threadIdx.x;
  const int CHB = CH / 8;
  if (i >= 128 * 176 * CHB) return;
  int e = i % CHB, q = i / CHB;
  int r = q / 176, p = q % 176;
  int row, col;
  if (p < 64) { row = (p >> 5) * 29; col = p & 31; }
  else { int q2 = p - 64; row = 1 + (q2 >> 2); int cc = q2 & 3; col = cc ? (28 + cc) : 0; }
  u32x4 z = {0, 0, 0, 0};
  *(u32x4*)&X[(((size_t)r * 30 + row) * 32 + col) * CH + e * 8] = z;
}

// ---------------- bilinear resize 56->28 ----------------
__device__ inline int resize_taps(int i, int* rows, float* wts) {
  if (i == 0) {
    rows[0] = 0; rows[1] = 1; rows[2] = 2;
    wts[0] = 3.f / 7.f; wts[1] = 3.f / 7.f; wts[2] = 1.f / 7.f; return 3;
  }
  if (i == 27) {
    rows[0] = 53; rows[1] = 54; rows[2] = 55;
    wts[0] = 1.f / 7.f; wts[1] = 3.f / 7.f; wts[2] = 3.f / 7.f; return 3;
  }
  rows[0] = 2 * i - 1; rows[1] = 2 * i; rows[2] = 2 * i + 1; rows[3] = 2 * i + 2;
  wts[0] = 0.125f; wts[1] = 0.375f; wts[2] = 0.375f; wts[3] = 0.125f; return 4;
}

__global__ __launch_bounds__(256) void k_resize(
    const float* __restrict__ ma_in, const float* __restrict__ mb_in,
    float* __restrict__ m_a28, float* __restrict__ m_b28,
    float* __restrict__ ma_sum) {
  int r = blockIdx.x, side = blockIdx.y, t = threadIdx.x;
  const float* in = (side ? mb_in : ma_in) + (size_t)r * 3136;
  float* out = (side ? m_b28 : m_a28) + (size_t)r * 784;
  float cnt = 0.f;
  for (int p = t; p < 784; p += 256) {
    int i = p / 28, j = p % 28;
    int rr_[4], cc_[4]; float wr[4], wc[4];
    int nr = resize_taps(i, rr_, wr), nc = resize_taps(j, cc_, wc);
    float v = 0.f;
    for (int a = 0; a < nr; ++a) {
      float rv = 0.f;
      for (int b = 0; b < nc; ++b) rv += wc[b] * in[rr_[a] * 56 + cc_[b]];
      v += wr[a] * rv;
    }
    out[p] = v;
    cnt += (v >= 0.f) ? 1.f : 0.f;
  }
  __shared__ float red[4];
  for (int off = 32; off; off >>= 1) cnt += __shfl_xor(cnt, off, 64);
  int lane = t & 63, wid = t >> 6;
  if (lane == 0) red[wid] = cnt;
  __syncthreads();
  if (t == 0 && side == 0) ma_sum[r] = red[0] + red[1] + red[2] + red[3];
}

// ---------------- gap + conv2(gap) ----------------
__global__ __launch_bounds__(256) void k_gap(
    const float* __restrict__ feat_a, const float* __restrict__ m_a28,
    const float* __restrict__ ma_sum, float* __restrict__ gap) {
  int r = blockIdx.y, wid = threadIdx.x >> 6, lane = threadIdx.x & 63;
  int c = blockIdx.x * 4 + wid;
  const float* x = feat_a + ((size_t)r * 256 + c) * 784;
  const float* m = m_a28 + (size_t)r * 784;
  float s = 0.f;
  for (int n = lane; n < 784; n += 64)
    s += x[n] * ((m[n] >= 0.f) ? 1.f : 0.f);
  for (int off = 32; off; off >>= 1) s += __shfl_xor(s, off, 64);
  if (lane == 0) gap[r * 256 + c] = s / (ma_sum[r] + 1e-5f);
}

__global__ __launch_bounds__(256) void k_gap2(
    const float* __restrict__ gap, const float* __restrict__ w2t,
    const float* __restrict__ b2, float* __restrict__ gap2) {
  int r = blockIdx.x, t = threadIdx.x;
  __shared__ float g[256];
  g[t] = gap[r * 256 + t];
  __syncthreads();
  float acc = b2[t];
  for (int ic = 0; ic < 256; ++ic) acc += w2t[ic * 256 + t] * g[ic];
  gap2[r * 256 + t] = acc;
}

// ---------------- EM ----------------
__global__ __launch_bounds__(256) void k_em_init(
    const float* __restrict__ pos_mu, const float* __restrict__ neg_mu,
    float* __restrict__ mu) {
  int r = blockIdx.x, t = threadIdx.x;
  float* o = mu + (size_t)r * 2048 + t * 8;
#pragma unroll
  for (int k = 0; k < 4; ++k) {
    o[k] = pos_mu[t * 4 + k];
    o[k + 4] = neg_mu[t * 4 + k];
  }
}

// fused stage: 49-px tile; x staged once in LDS; z-step + partial munew + z-sums
__global__ __launch_bounds__(256) void k_em_F(
    const float* __restrict__ x, const float* __restrict__ mres,
    const float* __restrict__ mu, float* __restrict__ mn_part,
    float* __restrict__ ps_part) {
  __shared__ float xs[256][53];             // 54.3 KB, pad 53 (odd) -> conflict-free
  __shared__ float Sp[4][49][8];            // partial S; Sp[0] reused as z
  __shared__ __align__(16) float muL[256][8];
  int tile = blockIdx.x, r = blockIdx.y, t = threadIdx.x;
  int n0 = tile * 49;
  {
    const f32x4* src = (const f32x4*)(mu + (size_t)r * 2048);
    f32x4 a = src[t * 2], b = src[t * 2 + 1];
    *(f32x4*)&muL[t][0] = a; *(f32x4*)&muL[t][4] = b;
  }
  const float* xb = x + (size_t)r * 200704 + n0;
  for (int i = t; i < 12544; i += 256) {
    int c = i / 49, j = i - c * 49;
    xs[c][j] = xb[c * 784 + j];
  }
  __syncthreads();
  // pass A: 4 c-groups x 49 px
  if (t < 196) {
    int g = t / 49, n = t - g * 49;
    float S[8] = {0, 0, 0, 0, 0, 0, 0, 0};
#pragma unroll 8
    for (int cc = 0; cc < 64; ++cc) {
      int c = g * 64 + cc;
      float xv = xs[c][n];
      f32x4 a = *(const f32x4*)&muL[c][0];
      f32x4 b = *(const f32x4*)&muL[c][4];
      S[0] += xv * a.x; S[1] += xv * a.y; S[2] += xv * a.z; S[3] += xv * a.w;
      S[4] += xv * b.x; S[5] += xv * b.y; S[6] += xv * b.z; S[7] += xv * b.w;
    }
#pragma unroll
    for (int k = 0; k < 8; ++k) Sp[g][n][k] = S[k];
  }
  __syncthreads();
  if (t < 49) {
    float S[8];
#pragma unroll
    for (int k = 0; k < 8; ++k)
      S[k] = Sp[0][t][k] + Sp[1][t][k] + Sp[2][t][k] + Sp[3][t][k];
    float m = (mres[(size_t)r * 784 + n0 + t] >= 0.f) ? 1.f : 0.f;
    float mxp = fmaxf(fmaxf(S[0], S[1]), fmaxf(S[2], S[3]));
    float e0 = expf(20.f * (S[0] - mxp)), e1 = expf(20.f * (S[1] - mxp));
    float e2 = expf(20.f * (S[2] - mxp)), e3 = expf(20.f * (S[3] - mxp));
    float dp = m / (e0 + e1 + e2 + e3);
    float mxn = fmaxf(fmaxf(S[4], S[5]), fmaxf(S[6], S[7]));
    float f0 = expf(20.f * (S[4] - mxn)), f1 = expf(20.f * (S[5] - mxn));
    float f2 = expf(20.f * (S[6] - mxn)), f3 = expf(20.f * (S[7] - mxn));
    float dn = (1.f - m) / (f0 + f1 + f2 + f3);
    Sp[0][t][0] = e0 * dp; Sp[0][t][1] = e1 * dp;
    Sp[0][t][2] = e2 * dp; Sp[0][t][3] = e3 * dp;
    Sp[0][t][4] = f0 * dn; Sp[0][t][5] = f1 * dn;
    Sp[0][t][6] = f2 * dn; Sp[0][t][7] = f3 * dn;
  }
  __syncthreads();
  if (t < 8) {
    float s = 0.f;
    for (int n = 0; n < 49; ++n) s += Sp[0][n][t];
    ps_part[((size_t)r * 16 + tile) * 8 + t] = s;
  }
  // pass B: thread t = channel c
  float acc[8] = {0, 0, 0, 0, 0, 0, 0, 0};
  for (int n = 0; n < 49; ++n) {
    float xv = xs[t][n];
    f32x4 z0 = *(const f32x4*)&Sp[0][n][0];
    f32x4 z1 = *(const f32x4*)&Sp[0][n][4];
    acc[0] += xv * z0.x; acc[1] += xv * z0.y; acc[2] += xv * z0.z; acc[3] += xv * z0.w;
    acc[4] += xv * z1.x; acc[5] += xv * z1.y; acc[6] += xv * z1.z; acc[7] += xv * z1.w;
  }
  float* o = mn_part + (((size_t)r * 16 + tile) * 256 + t) * 8;
  *(f32x4*)&o[0] = f32x4{acc[0], acc[1], acc[2], acc[3]};
  *(f32x4*)&o[4] = f32x4{acc[4], acc[5], acc[6], acc[7]};
}

// reduce: sum 16 partials, exact l1+l2 fold, write mu
__global__ __launch_bounds__(256) void k_em_R(
    const float* __restrict__ mn_part, const float* __restrict__ ps_part,
    float* __restrict__ mu) {
  __shared__ float redsh[4][8];
  __shared__ float csv[8];
  __shared__ float inv[8];
  int r = blockIdx.x, t = threadIdx.x, lane = t & 63, wid = t >> 6;
  float mn[8] = {0, 0, 0, 0, 0, 0, 0, 0};
#pragma unroll
  for (int tile = 0; tile < 16; ++tile) {
    const float* p = mn_part + (((size_t)r * 16 + tile) * 256 + t) * 8;
    f32x4 a = *(const f32x4*)&p[0];
    f32x4 b = *(const f32x4*)&p[4];
    mn[0] += a.x; mn[1] += a.y; mn[2] += a.z; mn[3] += a.w;
    mn[4] += b.x; mn[5] += b.y; mn[6] += b.z; mn[7] += b.w;
  }
  if (t < 8) {
    float s = 0.f;
#pragma unroll
    for (int tile = 0; tile < 16; ++tile)
      s += ps_part[((size_t)r * 16 + tile) * 8 + t];
    csv[t] = s;
  }
  float sq[8];
#pragma unroll
  for (int k = 0; k < 8; ++k) sq[k] = mn[k] * mn[k];
#pragma unroll
  for (int k = 0; k < 8; ++k)
    for (int off = 32; off; off >>= 1) sq[k] += __shfl_xor(sq[k], off, 64);
  if (lane == 0) {
#pragma unroll
    for (int k = 0; k < 8; ++k) redsh[wid][k] = sq[k];
  }
  __syncthreads();
  if (t < 8) {
    float rn = redsh[0][t] + redsh[1][t] + redsh[2][t] + redsh[3][t];
    float s = 1.f / (1e-6f + csv[t]);
    inv[t] = s / (1e-6f + s * sqrtf(rn));
  }
  __syncthreads();
  float* o = mu + (size_t)r * 2048 + t * 8;
  *(f32x4*)&o[0] = f32x4{mn[0] * inv[0], mn[1] * inv[1], mn[2] * inv[2], mn[3] * inv[3]};
  *(f32x4*)&o[4] = f32x4{mn[4] * inv[4], mn[5] * inv[5], mn[6] * inv[6], mn[7] * inv[7]};
}

__global__ __launch_bounds__(256) void k_em_prop(
    const float* __restrict__ xb, const float* __restrict__ mu,
    float* __restrict__ pos_z, float* __restrict__ neg_z) {
  __shared__ __align__(16) float muL[256][8];
  int r = blockIdx.y, t = threadIdx.x;
  {
    const f32x4* src = (const f32x4*)(mu + (size_t)r * 2048);
    f32x4 a = src[t * 2], b = src[t * 2 + 1];
    *(f32x4*)&muL[t][0] = a; *(f32x4*)&muL[t][4] = b;
  }
  __syncthreads();
  if (t >= 196) return;
  int n = blockIdx.x * 196 + t;
  const float* xp = xb + (size_t)r * 200704 + n;
  float S[8] = {0, 0, 0, 0, 0, 0, 0, 0};
#pragma unroll 8
  for (int c = 0; c < 256; ++c) {
    float xv = xp[c * 784];
    f32x4 a = *(const f32x4*)&muL[c][0];
    f32x4 b = *(const f32x4*)&muL[c][4];
    S[0] += xv * a.x; S[1] += xv * a.y; S[2] += xv * a.z; S[3] += xv * a.w;
    S[4] += xv * b.x; S[5] += xv * b.y; S[6] += xv * b.z; S[7] += xv * b.w;
  }
  float mx = S[0];
#pragma unroll
  for (int k = 1; k < 8; ++k) mx = fmaxf(mx, S[k]);
  float e[8], d = 0.f;
#pragma unroll
  for (int k = 0; k < 8; ++k) { e[k] = expf(S[k] - mx); d += e[k]; }
  float invd = 1.f / d;
  pos_z[(size_t)r * 784 + n] = (e[0] + e[1] + e[2] + e[3]) * invd;
  neg_z[(size_t)r * 784 + n] = (e[4] + e[5] + e[6] + e[7]) * invd;
}

// ---------------- build conv1 input: NHWC-padded bf16 [r][30][32][288] ------
__global__ __launch_bounds__(256) void k_mkxin(
    const float* __restrict__ feat_b, const float* __restrict__ pos_z,
    const float* __restrict__ neg_z, const float* __restrict__ m_a28,
    u16* __restrict__ Xin) {
  __shared__ u16 tile[32][65];
  int pt = blockIdx.x, cb = blockIdx.y, r = blockIdx.z;
  int t = threadIdx.x, w = t >> 6, lane = t & 63;
  int p0 = pt * 56;
#pragma unroll
  for (int i2 = 0; i2 < 8; ++i2) {
    int cl = w * 8 + i2;
    float v = 0.f;
    if (lane < 56) {
      int n = p0 + lane;
      if (cb < 8) v = feat_b[((size_t)r * 256 + cb * 32 + cl) * 784 + n];
      else if (cl == 0) v = pos_z[(size_t)r * 784 + n];
      else if (cl == 1) v = neg_z[(size_t)r * 784 + n];
      else if (cl == 2) v = m_a28[(size_t)r * 784 + n];
    }
    tile[cl][lane] = f2bf(v);
  }
  __syncthreads();
  int pl = t >> 2, eo = t & 3;
  if (pl < 56) {
    int n = p0 + pl, row = n / 28 + 1, col = n % 28 + 1;
    __align__(16) u16 o[8];
#pragma unroll
    for (int j2 = 0; j2 < 8; ++j2) o[j2] = tile[eo * 8 + j2][pl];
    *(u32x4*)&Xin[(((size_t)r * 30 + row) * 32 + col) * 288 + cb * 32 + eo * 8] =
        *(u32x4*)o;
  }
}

// ---- MFMA 3x3 conv: implicit GEMM, 4-row strips, constexpr phases ----------
template <int CH, bool IS1, bool RELU>
__global__ __launch_bounds__(256, 2) void k_convm(
    const u16* __restrict__ Xin, const u16* __restrict__ wpk,
    const float* __restrict__ bias, const float* __restrict__ gap2,
    u16* __restrict__ Xout) {
  constexpr int KSPT = CH / 32;            // 8 or 9
  constexpr int NFULL = KSPT / 2;          // 4 full phases (ks=2, ne=8)
  constexpr bool TAIL = (KSPT & 1) != 0;   // CH==288 extra ks=1 phase
  __shared__ __align__(16) u16 lds[192 * 64];  // 24KB
  int r = blockIdx.y, strip = blockIdx.x;
  int h0 = strip * 4;
  int t = threadIdx.x, w = t >> 6, lane = t & 63;
  size_t base_u = ((size_t)r * 30 + h0) * 32 * CH;
  int kb = lane >> 4;
  int pr = (lane & 15) >> 2, pc = lane & 3;
  f32x4 acc[4][7];
#pragma unroll
  for (int i = 0; i < 4; ++i)
#pragma unroll
    for (int p = 0; p < 7; ++p) acc[i][p] = f32x4{0.f, 0.f, 0.f, 0.f};
  const u16* wbase = wpk + ((size_t)(w * 4) * 64 + lane) * 8;
  for (int ph = 0; ph < NFULL; ++ph) {
    if (ph) __syncthreads();
#pragma unroll
    for (int c0 = 0; c0 < 6; ++c0) {       // 192*8/256
      int c = c0 * 256 + t;
      int pix = c >> 3, e = c & 7;
      u32x4 v = *(const u32x4*)&Xin[base_u + (size_t)pix * CH + (ph * 8 + e) * 8];
      *(u32x4*)&lds[(pix * 8 + (e ^ swz_of(pix))) * 8] = v;
    }
    __syncthreads();
    __builtin_amdgcn_s_setprio(1);
#pragma unroll
    for (int kq = 0; kq < 9; ++kq) {
      int dh = kq / 3, dw = kq % 3;
      int pixq = (pr + dh) * 32 + pc + dw;
#pragma unroll
      for (int ks = 0; ks < 2; ++ks) {
        int kk = kq * KSPT + ph * 2 + ks;
        short8 A[4];
#pragma unroll
        for (int i = 0; i < 4; ++i)
          A[i] = *(const short8*)(wbase + (size_t)(kk * 16 + i) * 512);
        int e = ks * 4 + kb;
#pragma unroll
        for (int p = 0; p < 7; ++p) {
          int lp = pixq + 4 * p;
          short8 B = *(const short8*)&lds[(lp * 8 + (e ^ swz_of(lp))) * 8];
#pragma unroll
          for (int i = 0; i < 4; ++i)
            acc[i][p] =
                __builtin_amdgcn_mfma_f32_16x16x32_bf16(A[i], B, acc[i][p], 0, 0, 0);
        }
      }
    }
    __builtin_amdgcn_s_setprio(0);
  }
  if constexpr (TAIL) {
    __syncthreads();
#pragma unroll
    for (int c0 = 0; c0 < 3; ++c0) {       // 192*4/256
      int c = c0 * 256 + t;
      int pix = c >> 2, e = c & 3;
      u32x4 v = *(const u32x4*)&Xin[base_u + (size_t)pix * CH +
                                    ((size_t)(KSPT - 1) * 4 + e) * 8];
      *(u32x4*)&lds[(pix * 8 + slot4(e, pix)) * 8] = v;
    }
    __syncthreads();
    __builtin_amdgcn_s_setprio(1);
#pragma unroll
    for (int kq = 0; kq < 9; ++kq) {
      int dh = kq / 3, dw = kq % 3;
      int pixq = (pr + dh) * 32 + pc + dw;
      int kk = kq * KSPT + KSPT - 1;
      short8 A[4];
#pragma unroll
      for (int i = 0; i < 4; ++i)
        A[i] = *(const short8*)(wbase + (size_t)(kk * 16 + i) * 512);
#pragma unroll
      for (int p = 0; p < 7; ++p) {
        int lp = pixq + 4 * p;
        short8 B = *(const short8*)&lds[(lp * 8 + slot4(kb, lp)) * 8];
#pragma unroll
        for (int i = 0; i < 4; ++i)
          acc[i][p] =
              __builtin_amdgcn_mfma_f32_16x16x32_bf16(A[i], B, acc[i][p], 0, 0, 0);
      }
    }
    __builtin_amdgcn_s_setprio(0);
  }
  // epilogue: D row = kb*4+reg (oc), col = lane&15 (pixel)
#pragma unroll
  for (int i = 0; i < 4; ++i) {
    int oc = (w * 4 + i) * 16 + kb * 4;
    f32x4 bb = *(const f32x4*)&bias[oc];
    if (IS1) bb += *(const f32x4*)&gap2[r * 256 + oc];
#pragma unroll
    for (int p = 0; p < 7; ++p) {
      f32x4 v = acc[i][p] + bb;
      if (RELU) {
        v.x = fmaxf(v.x, 0.f); v.y = fmaxf(v.y, 0.f);
        v.z = fmaxf(v.z, 0.f); v.w = fmaxf(v.w, 0.f);
      }
      __align__(8) u16 o[4] = {f2bf(v.x), f2bf(v.y), f2bf(v.z), f2bf(v.w)};
      int orow = h0 + pr + 1, ocol = 4 * p + pc + 1;
      *(u32x2*)&Xout[(((size_t)r * 30 + orow) * 32 + ocol) * 256 + oc] = *(u32x2*)o;
    }
  }
}

// ---------------- MFMA deconv(2x2,s2) + relu + 1x1 logits ----------------
__global__ __launch_bounds__(256, 2) void k_deconvm(
    const u16* __restrict__ X, const u16* __restrict__ wpkd,
    const float* __restrict__ db, const float* __restrict__ lw,
    const float* __restrict__ lb, float* __restrict__ out) {
  __shared__ __align__(16) u16 lds[112 * 256];
  __shared__ float plog[4][112];
  int r = blockIdx.y, strip = blockIdx.x, h0 = strip * 4;
  int t = threadIdx.x, w = t >> 6, lane = t & 63;
  for (int c = t; c < 112 * 32; c += 256) {
    int ip = c >> 5, e = c & 31;
    int hh = ip / 28, ww = ip % 28;
    u32x4 v = *(const u32x4*)&X[(((size_t)r * 30 + h0 + hh + 1) * 32 + ww + 1) * 256 + e * 8];
    *(u32x4*)&lds[(ip * 32 + (e ^ swz_of(ip))) * 8] = v;
  }
  __syncthreads();
  int kb = lane >> 4, colp = lane & 15;
  float lbv = lb[0];
  f32x4 lw4[4], db4[4];
#pragma unroll
  for (int i = 0; i < 4; ++i) {
    int oc = (w * 4 + i) * 16 + kb * 4;
    lw4[i] = *(const f32x4*)&lw[oc];
    db4[i] = *(const f32x4*)&db[oc];
  }
  const u16* wbase = wpkd + ((size_t)(w * 4) * 64 + lane) * 8;
  for (int kl = 0; kl < 4; ++kl) {
    f32x4 acc[4][7];
#pragma unroll
    for (int i = 0; i < 4; ++i)
#pragma unroll
      for (int p = 0; p < 7; ++p) acc[i][p] = f32x4{0.f, 0.f, 0.f, 0.f};
    for (int ks = 0; ks < 8; ++ks) {
      int kk = kl * 8 + ks;
      short8 A[4];
#pragma unroll
      for (int i = 0; i < 4; ++i)
        A[i] = *(const short8*)(wbase + (size_t)(kk * 16 + i) * 512);
      int e = ks * 4 + kb;
#pragma unroll
      for (int p = 0; p < 7; ++p) {
        int ip = p * 16 + colp;
        short8 B = *(const short8*)&lds[((ip << 5) + (e ^ swz_of(ip))) * 8];
#pragma unroll
        for (int i = 0; i < 4; ++i)
          acc[i][p] =
              __builtin_amdgcn_mfma_f32_16x16x32_bf16(A[i], B, acc[i][p], 0, 0, 0);
      }
    }
#pragma unroll
    for (int p = 0; p < 7; ++p) {
      float s = 0.f;
#pragma unroll
      for (int i = 0; i < 4; ++i) {
        f32x4 v = acc[i][p] + db4[i];
        s += lw4[i].x * fmaxf(v.x, 0.f) + lw4[i].y * fmaxf(v.y, 0.f) +
             lw4[i].z * fmaxf(v.z, 0.f) + lw4[i].w * fmaxf(v.w, 0.f);
      }
      s += __shfl_xor(s, 16, 64);
      s += __shfl_xor(s, 32, 64);
      if (lane < 16) plog[w][p * 16 + lane] = s;
    }
    __syncthreads();
    if (t < 112) {
      float s = plog[0][t] + plog[1][t] + plog[2][t] + plog[3][t] + lbv;
      int hh = t / 28, ww = t % 28;
      int k = kl >> 1, l = kl & 1;
      out[(size_t)r * 3136 + (2 * (h0 + hh) + k) * 56 + 2 * ww + l] = s;
    }
    __syncthreads();
  }
}

// ---------------- launcher ----------------
extern "C" void kernel_launch(void* const* d_in, const int* in_sizes, int n_in,
                              void* d_out, int out_size, void* d_ws, size_t ws_size,
                              hipStream_t stream) {
  const float* feat_a = (const float*)d_in[0];
  const float* mask_a = (const float*)d_in[1];
  const float* feat_b = (const float*)d_in[2];
  const float* mask_b = (const float*)d_in[3];
  const float* pos_mu = (const float*)d_in[4];
  const float* neg_mu = (const float*)d_in[5];
  const float* conv1_w = (const float*)d_in[6];
  const float* conv1_b = (const float*)d_in[7];
  const float* conv2_w = (const float*)d_in[8];
  const float* conv2_b = (const float*)d_in[9];
  const float* convs_w = (const float*)d_in[10];
  const float* convs_b = (const float*)d_in[11];
  const float* deconv_w = (const float*)d_in[12];
  const float* deconv_b = (const float*)d_in[13];
  const float* logits_w = (const float*)d_in[14];
  const float* logits_b = (const float*)d_in[15];
  float* out = (float*)d_out;

  char* P = (char*)d_ws;
  auto alloc = [&](size_t bytes) {
    char* q = P;
    P += (bytes + 255) & ~(size_t)255;
    return q;
  };
  float* m_a28 = (float*)alloc(401408 * 4);
  float* m_b28 = (float*)alloc(401408 * 4);
  float* ma_sum = (float*)alloc(512);
  float* gap = (float*)alloc(131072 * 4);
  float* gap2 = (float*)alloc(131072 * 4);
  float* pos_z = (float*)alloc(401408 * 4);
  float* neg_z = (float*)alloc(401408 * 4);
  float* w2t = (float*)alloc(65536 * 4);
  float* mu = (float*)alloc(262144 * 4);
  float* mn_part = (float*)alloc((size_t)128 * 16 * 256 * 8 * 4);
  float* ps_part = (float*)alloc(128 * 16 * 8 * 4);
  u16* wpk1 = (u16*)alloc(663552 * 2);
  u16* wpk3 = (u16*)alloc(1769472 * 2);
  u16* wpkd = (u16*)alloc(262144 * 2);
  u16* Xin = (u16*)alloc((size_t)128 * 30 * 32 * 288 * 2);
  u16* A1 = (u16*)alloc((size_t)128 * 30 * 32 * 256 * 2);
  u16* A2 = (u16*)alloc((size_t)128 * 30 * 32 * 256 * 2);

  k_pack1<<<2592, 256, 0, stream>>>(conv1_w, wpk1);
  k_pack3<<<6912, 256, 0, stream>>>(convs_w, wpk3);
  k_packd<<<1024, 256, 0, stream>>>(deconv_w, wpkd);
  k_tw_conv2<<<256, 256, 0, stream>>>(conv2_w, w2t);
  k_halo<288><<<3168, 256, 0, stream>>>(Xin);
  k_halo<256><<<2816, 256, 0, stream>>>(A1);
  k_halo<256><<<2816, 256, 0, stream>>>(A2);

  k_resize<<<dim3(128, 2), 256, 0, stream>>>(mask_a, mask_b, m_a28, m_b28, ma_sum);
  k_gap<<<dim3(64, 128), 256, 0, stream>>>(feat_a, m_a28, ma_sum, gap);
  k_gap2<<<128, 256, 0, stream>>>(gap, w2t, conv2_b, gap2);

  k_em_init<<<128, 256, 0, stream>>>(pos_mu, neg_mu, mu);
  for (int phase = 0; phase < 2; ++phase) {
    const float* x = phase ? feat_b : feat_a;
    const float* mm = phase ? m_b28 : m_a28;
    for (int s = 0; s < 6; ++s) {
      k_em_F<<<dim3(16, 128), 256, 0, stream>>>(x, mm, mu, mn_part, ps_part);
      k_em_R<<<128, 256, 0, stream>>>(mn_part, ps_part, mu);
    }
  }
  k_em_prop<<<dim3(4, 128), 256, 0, stream>>>(feat_b, mu, pos_z, neg_z);

  k_mkxin<<<dim3(14, 9, 128), 256, 0, stream>>>(feat_b, pos_z, neg_z, m_a28, Xin);

  k_convm<288, true, false><<<dim3(7, 128), 256, 0, stream>>>(
      Xin, wpk1, conv1_b, gap2, A1);
  k_convm<256, false, true><<<dim3(7, 128), 256, 0, stream>>>(
      A1, wpk3, convs_b, nullptr, A2);
  k_convm<256, false, true><<<dim3(7, 128), 256, 0, stream>>>(
      A2, wpk3 + 589824, convs_b + 256, nullptr, A1);
  k_convm<256, false, true><<<dim3(7, 128), 256, 0, stream>>>(
      A1, wpk3 + 2 * 589824, convs_b + 512, nullptr, A2);

  k_deconvm<<<dim3(7, 128), 256, 0, stream>>>(A2, wpkd, deconv_b, logits_w,
                                              logits_b, out);
}

// Round 12
// 1420.140 us; speedup vs baseline: 1.0034x; 1.0034x over previous
//
#include <hip/hip_runtime.h>
#include <cstddef>

typedef unsigned short u16;
typedef unsigned int u32;
typedef __attribute__((ext_vector_type(8))) short short8;
typedef __attribute__((ext_vector_type(4))) float f32x4;
typedef __attribute__((ext_vector_type(4))) u32 u32x4;
typedef __attribute__((ext_vector_type(2))) u32 u32x2;

__device__ inline u16 f2bf(float x) {
  union { float f; u32 u; } v; v.f = x;
  u32 r = v.u + 0x7fffu + ((v.u >> 16) & 1u);
  return (u16)(r >> 16);
}
__device__ inline int swz_of(int pix) {
  return (((pix >> 5) & 1) << 2) ^ (pix & 7);
}
// conv staging slot: bank = (slot*4+word)%32 (pixel drops out), so slot must
// spread over all 8 residues across a 16-lane read group (4 cols x 2 row-par).
__device__ inline int cslot(int ne, int e, int pix) {
  return (ne == 8) ? (e ^ swz_of(pix))
                   : ((e ^ (pix & 3)) | ((((pix >> 2) ^ (pix >> 5)) & 1) << 2));
}

// ---------------- weight packing (MFMA A-fragment order, bf16) ----------------
__global__ void k_pack1(const float* __restrict__ w, u16* __restrict__ wpk) {
  int i = blockIdx.x * 256 + threadIdx.x;  // 81*16*512
  if (i >= 663552) return;
  int j = i & 7, l = (i >> 3) & 63, ot = (i >> 9) & 15, kk = i >> 13;
  int kq = kk / 9, ks = kk % 9;
  int ic = ks * 32 + (l >> 4) * 8 + j;
  int oc = ot * 16 + (l & 15);
  float v = (ic < 259) ? w[(oc * 259 + ic) * 9 + kq] : 0.f;
  wpk[i] = f2bf(v);
}
__global__ void k_pack3(const float* __restrict__ w, u16* __restrict__ wpk) {
  int i = blockIdx.x * 256 + threadIdx.x;  // 3*72*16*512
  if (i >= 1769472) return;
  int j = i & 7, l = (i >> 3) & 63, ot = (i >> 9) & 15, kk2 = i >> 13;
  int ll = kk2 / 72, kk = kk2 % 72;
  int kq = kk / 8, ks = kk % 8;
  int ic = ks * 32 + (l >> 4) * 8 + j;
  int oc = ot * 16 + (l & 15);
  wpk[i] = f2bf(w[((ll * 256 + oc) * 256 + ic) * 9 + kq]);
}
__global__ void k_packd(const float* __restrict__ w, u16* __restrict__ wpk) {
  int i = blockIdx.x * 256 + threadIdx.x;  // 32*16*512
  if (i >= 262144) return;
  int j = i & 7, l = (i >> 3) & 63, ot = (i >> 9) & 15, kk = i >> 13;
  int kl = kk / 8, ks = kk % 8;
  int ic = ks * 32 + (l >> 4) * 8 + j;
  int oc = ot * 16 + (l & 15);
  wpk[i] = f2bf(w[(ic * 256 + oc) * 4 + kl]);
}
__global__ void k_tw_conv2(const float* __restrict__ w, float* __restrict__ wt) {
  int i = blockIdx.x * 256 + threadIdx.x;
  if (i >= 256 * 256) return;
  int oc = i & 255, ic = i >> 8;
  wt[i] = w[oc * 256 + ic];
}

// ---------------- zero halos of NHWC-padded bf16 activation buffers ----------
template <int CH>
__global__ void k_halo(u16* __restrict__ X) {
  int i = blockIdx.x * 256 + threadIdx.x;
  const int CHB = CH / 8;
  if (i >= 128 * 176 * CHB) return;
  int e = i % CHB, q = i / CHB;
  int r = q / 176, p = q % 176;
  int row, col;
  if (p < 64) { row = (p >> 5) * 29; col = p & 31; }
  else { int q2 = p - 64; row = 1 + (q2 >> 2); int cc = q2 & 3; col = cc ? (28 + cc) : 0; }
  u32x4 z = {0, 0, 0, 0};
  *(u32x4*)&X[(((size_t)r * 30 + row) * 32 + col) * CH + e * 8] = z;
}

// ---------------- bilinear resize 56->28 ----------------
__device__ inline int resize_taps(int i, int* rows, float* wts) {
  if (i == 0) {
    rows[0] = 0; rows[1] = 1; rows[2] = 2;
    wts[0] = 3.f / 7.f; wts[1] = 3.f / 7.f; wts[2] = 1.f / 7.f; return 3;
  }
  if (i == 27) {
    rows[0] = 53; rows[1] = 54; rows[2] = 55;
    wts[0] = 1.f / 7.f; wts[1] = 3.f / 7.f; wts[2] = 3.f / 7.f; return 3;
  }
  rows[0] = 2 * i - 1; rows[1] = 2 * i; rows[2] = 2 * i + 1; rows[3] = 2 * i + 2;
  wts[0] = 0.125f; wts[1] = 0.375f; wts[2] = 0.375f; wts[3] = 0.125f; return 4;
}

__global__ __launch_bounds__(256) void k_resize(
    const float* __restrict__ ma_in, const float* __restrict__ mb_in,
    float* __restrict__ m_a28, float* __restrict__ m_b28,
    float* __restrict__ ma_sum) {
  int r = blockIdx.x, side = blockIdx.y, t = threadIdx.x;
  const float* in = (side ? mb_in : ma_in) + (size_t)r * 3136;
  float* out = (side ? m_b28 : m_a28) + (size_t)r * 784;
  float cnt = 0.f;
  for (int p = t; p < 784; p += 256) {
    int i = p / 28, j = p % 28;
    int rr_[4], cc_[4]; float wr[4], wc[4];
    int nr = resize_taps(i, rr_, wr), nc = resize_taps(j, cc_, wc);
    float v = 0.f;
    for (int a = 0; a < nr; ++a) {
      float rv = 0.f;
      for (int b = 0; b < nc; ++b) rv += wc[b] * in[rr_[a] * 56 + cc_[b]];
      v += wr[a] * rv;
    }
    out[p] = v;
    cnt += (v >= 0.f) ? 1.f : 0.f;
  }
  __shared__ float red[4];
  for (int off = 32; off; off >>= 1) cnt += __shfl_xor(cnt, off, 64);
  int lane = t & 63, wid = t >> 6;
  if (lane == 0) red[wid] = cnt;
  __syncthreads();
  if (t == 0 && side == 0) ma_sum[r] = red[0] + red[1] + red[2] + red[3];
}

// ---------------- gap + conv2(gap) ----------------
__global__ __launch_bounds__(256) void k_gap(
    const float* __restrict__ feat_a, const float* __restrict__ m_a28,
    const float* __restrict__ ma_sum, float* __restrict__ gap) {
  int r = blockIdx.y, wid = threadIdx.x >> 6, lane = threadIdx.x & 63;
  int c = blockIdx.x * 4 + wid;
  const float* x = feat_a + ((size_t)r * 256 + c) * 784;
  const float* m = m_a28 + (size_t)r * 784;
  float s = 0.f;
  for (int n = lane; n < 784; n += 64)
    s += x[n] * ((m[n] >= 0.f) ? 1.f : 0.f);
  for (int off = 32; off; off >>= 1) s += __shfl_xor(s, off, 64);
  if (lane == 0) gap[r * 256 + c] = s / (ma_sum[r] + 1e-5f);
}

__global__ __launch_bounds__(256) void k_gap2(
    const float* __restrict__ gap, const float* __restrict__ w2t,
    const float* __restrict__ b2, float* __restrict__ gap2) {
  int r = blockIdx.x, t = threadIdx.x;
  __shared__ float g[256];
  g[t] = gap[r * 256 + t];
  __syncthreads();
  float acc = b2[t];
  for (int ic = 0; ic < 256; ++ic) acc += w2t[ic * 256 + t] * g[ic];
  gap2[r * 256 + t] = acc;
}

// ---------------- EM ----------------
__global__ __launch_bounds__(256) void k_em_init(
    const float* __restrict__ pos_mu, const float* __restrict__ neg_mu,
    float* __restrict__ mu) {
  int r = blockIdx.x, t = threadIdx.x;
  float* o = mu + (size_t)r * 2048 + t * 8;
#pragma unroll
  for (int k = 0; k < 4; ++k) {
    o[k] = pos_mu[t * 4 + k];
    o[k + 4] = neg_mu[t * 4 + k];
  }
}

// fused stage: 28-px tile; x staged once in LDS; z-step + partial munew + z-sums
__global__ __launch_bounds__(256) void k_em_F(
    const float* __restrict__ x, const float* __restrict__ mres,
    const float* __restrict__ mu, float* __restrict__ mn_part,
    float* __restrict__ ps_part) {
  __shared__ float xs[256][29];             // 29.7 KB, odd pad -> conflict-free
  __shared__ float Sp[8][28][8];            // partial S; Sp[0] reused as z
  __shared__ __align__(16) float muL[256][8];
  int tile = blockIdx.x, r = blockIdx.y, t = threadIdx.x;
  int n0 = tile * 28;
  {
    const f32x4* src = (const f32x4*)(mu + (size_t)r * 2048);
    f32x4 a = src[t * 2], b = src[t * 2 + 1];
    *(f32x4*)&muL[t][0] = a; *(f32x4*)&muL[t][4] = b;
  }
  const float* xb = x + (size_t)r * 200704 + n0;
  for (int i = t; i < 7168; i += 256) {
    int c = i / 28, j = i - c * 28;
    xs[c][j] = xb[c * 784 + j];
  }
  __syncthreads();
  // pass A: 8 c-groups x 28 px
  if (t < 224) {
    int g = t / 28, n = t - g * 28;
    float S[8] = {0, 0, 0, 0, 0, 0, 0, 0};
#pragma unroll 8
    for (int cc = 0; cc < 32; ++cc) {
      int c = g * 32 + cc;
      float xv = xs[c][n];
      f32x4 a = *(const f32x4*)&muL[c][0];
      f32x4 b = *(const f32x4*)&muL[c][4];
      S[0] += xv * a.x; S[1] += xv * a.y; S[2] += xv * a.z; S[3] += xv * a.w;
      S[4] += xv * b.x; S[5] += xv * b.y; S[6] += xv * b.z; S[7] += xv * b.w;
    }
#pragma unroll
    for (int k = 0; k < 8; ++k) Sp[g][n][k] = S[k];
  }
  __syncthreads();
  if (t < 28) {
    float S[8];
#pragma unroll
    for (int k = 0; k < 8; ++k) {
      float s = 0.f;
#pragma unroll
      for (int g = 0; g < 8; ++g) s += Sp[g][t][k];
      S[k] = s;
    }
    float m = (mres[(size_t)r * 784 + n0 + t] >= 0.f) ? 1.f : 0.f;
    float mxp = fmaxf(fmaxf(S[0], S[1]), fmaxf(S[2], S[3]));
    float e0 = expf(20.f * (S[0] - mxp)), e1 = expf(20.f * (S[1] - mxp));
    float e2 = expf(20.f * (S[2] - mxp)), e3 = expf(20.f * (S[3] - mxp));
    float dp = m / (e0 + e1 + e2 + e3);
    float mxn = fmaxf(fmaxf(S[4], S[5]), fmaxf(S[6], S[7]));
    float f0 = expf(20.f * (S[4] - mxn)), f1 = expf(20.f * (S[5] - mxn));
    float f2 = expf(20.f * (S[6] - mxn)), f3 = expf(20.f * (S[7] - mxn));
    float dn = (1.f - m) / (f0 + f1 + f2 + f3);
    Sp[0][t][0] = e0 * dp; Sp[0][t][1] = e1 * dp;
    Sp[0][t][2] = e2 * dp; Sp[0][t][3] = e3 * dp;
    Sp[0][t][4] = f0 * dn; Sp[0][t][5] = f1 * dn;
    Sp[0][t][6] = f2 * dn; Sp[0][t][7] = f3 * dn;
  }
  __syncthreads();
  if (t < 8) {
    float s = 0.f;
    for (int n = 0; n < 28; ++n) s += Sp[0][n][t];
    ps_part[((size_t)r * 28 + tile) * 8 + t] = s;
  }
  // pass B: thread t = channel c
  float acc[8] = {0, 0, 0, 0, 0, 0, 0, 0};
#pragma unroll 4
  for (int n = 0; n < 28; ++n) {
    float xv = xs[t][n];
    f32x4 z0 = *(const f32x4*)&Sp[0][n][0];
    f32x4 z1 = *(const f32x4*)&Sp[0][n][4];
    acc[0] += xv * z0.x; acc[1] += xv * z0.y; acc[2] += xv * z0.z; acc[3] += xv * z0.w;
    acc[4] += xv * z1.x; acc[5] += xv * z1.y; acc[6] += xv * z1.z; acc[7] += xv * z1.w;
  }
  float* o = mn_part + (((size_t)r * 28 + tile) * 256 + t) * 8;
  *(f32x4*)&o[0] = f32x4{acc[0], acc[1], acc[2], acc[3]};
  *(f32x4*)&o[4] = f32x4{acc[4], acc[5], acc[6], acc[7]};
}

// reduce: sum 28 partials, exact l1+l2 fold, write mu
__global__ __launch_bounds__(256) void k_em_R(
    const float* __restrict__ mn_part, const float* __restrict__ ps_part,
    float* __restrict__ mu) {
  __shared__ float redsh[4][8];
  __shared__ float csv[8];
  __shared__ float inv[8];
  int r = blockIdx.x, t = threadIdx.x, lane = t & 63, wid = t >> 6;
  float mn[8] = {0, 0, 0, 0, 0, 0, 0, 0};
  for (int tile = 0; tile < 28; ++tile) {
    const float* p = mn_part + (((size_t)r * 28 + tile) * 256 + t) * 8;
    f32x4 a = *(const f32x4*)&p[0];
    f32x4 b = *(const f32x4*)&p[4];
    mn[0] += a.x; mn[1] += a.y; mn[2] += a.z; mn[3] += a.w;
    mn[4] += b.x; mn[5] += b.y; mn[6] += b.z; mn[7] += b.w;
  }
  if (t < 8) {
    float s = 0.f;
    for (int tile = 0; tile < 28; ++tile)
      s += ps_part[((size_t)r * 28 + tile) * 8 + t];
    csv[t] = s;
  }
  float sq[8];
#pragma unroll
  for (int k = 0; k < 8; ++k) sq[k] = mn[k] * mn[k];
#pragma unroll
  for (int k = 0; k < 8; ++k)
    for (int off = 32; off; off >>= 1) sq[k] += __shfl_xor(sq[k], off, 64);
  if (lane == 0) {
#pragma unroll
    for (int k = 0; k < 8; ++k) redsh[wid][k] = sq[k];
  }
  __syncthreads();
  if (t < 8) {
    float rn = redsh[0][t] + redsh[1][t] + redsh[2][t] + redsh[3][t];
    float s = 1.f / (1e-6f + csv[t]);
    inv[t] = s / (1e-6f + s * sqrtf(rn));
  }
  __syncthreads();
  float* o = mu + (size_t)r * 2048 + t * 8;
  *(f32x4*)&o[0] = f32x4{mn[0] * inv[0], mn[1] * inv[1], mn[2] * inv[2], mn[3] * inv[3]};
  *(f32x4*)&o[4] = f32x4{mn[4] * inv[4], mn[5] * inv[5], mn[6] * inv[6], mn[7] * inv[7]};
}

__global__ __launch_bounds__(256) void k_em_prop(
    const float* __restrict__ xb, const float* __restrict__ mu,
    float* __restrict__ pos_z, float* __restrict__ neg_z) {
  __shared__ __align__(16) float muL[256][8];
  int r = blockIdx.y, t = threadIdx.x;
  {
    const f32x4* src = (const f32x4*)(mu + (size_t)r * 2048);
    f32x4 a = src[t * 2], b = src[t * 2 + 1];
    *(f32x4*)&muL[t][0] = a; *(f32x4*)&muL[t][4] = b;
  }
  __syncthreads();
  if (t >= 196) return;
  int n = blockIdx.x * 196 + t;
  const float* xp = xb + (size_t)r * 200704 + n;
  float S[8] = {0, 0, 0, 0, 0, 0, 0, 0};
#pragma unroll 8
  for (int c = 0; c < 256; ++c) {
    float xv = xp[c * 784];
    f32x4 a = *(const f32x4*)&muL[c][0];
    f32x4 b = *(const f32x4*)&muL[c][4];
    S[0] += xv * a.x; S[1] += xv * a.y; S[2] += xv * a.z; S[3] += xv * a.w;
    S[4] += xv * b.x; S[5] += xv * b.y; S[6] += xv * b.z; S[7] += xv * b.w;
  }
  float mx = S[0];
#pragma unroll
  for (int k = 1; k < 8; ++k) mx = fmaxf(mx, S[k]);
  float e[8], d = 0.f;
#pragma unroll
  for (int k = 0; k < 8; ++k) { e[k] = expf(S[k] - mx); d += e[k]; }
  float invd = 1.f / d;
  pos_z[(size_t)r * 784 + n] = (e[0] + e[1] + e[2] + e[3]) * invd;
  neg_z[(size_t)r * 784 + n] = (e[4] + e[5] + e[6] + e[7]) * invd;
}

// ---------------- build conv1 input: NHWC-padded bf16 [r][30][32][288] ------
__global__ __launch_bounds__(256) void k_mkxin(
    const float* __restrict__ feat_b, const float* __restrict__ pos_z,
    const float* __restrict__ neg_z, const float* __restrict__ m_a28,
    u16* __restrict__ Xin) {
  __shared__ u16 tile[32][65];
  int pt = blockIdx.x, cb = blockIdx.y, r = blockIdx.z;
  int t = threadIdx.x, w = t >> 6, lane = t & 63;
  int p0 = pt * 56;
#pragma unroll
  for (int i2 = 0; i2 < 8; ++i2) {
    int cl = w * 8 + i2;
    float v = 0.f;
    if (lane < 56) {
      int n = p0 + lane;
      if (cb < 8) v = feat_b[((size_t)r * 256 + cb * 32 + cl) * 784 + n];
      else if (cl == 0) v = pos_z[(size_t)r * 784 + n];
      else if (cl == 1) v = neg_z[(size_t)r * 784 + n];
      else if (cl == 2) v = m_a28[(size_t)r * 784 + n];
    }
    tile[cl][lane] = f2bf(v);
  }
  __syncthreads();
  int pl = t >> 2, eo = t & 3;
  if (pl < 56) {
    int n = p0 + pl, row = n / 28 + 1, col = n % 28 + 1;
    __align__(16) u16 o[8];
#pragma unroll
    for (int j2 = 0; j2 < 8; ++j2) o[j2] = tile[eo * 8 + j2][pl];
    *(u32x4*)&Xin[(((size_t)r * 30 + row) * 32 + col) * 288 + cb * 32 + eo * 8] =
        *(u32x4*)o;
  }
}

// ---- MFMA 3x3 conv: implicit GEMM, 4-row strips, phased 24KB staging -------
template <int CH, bool IS1, bool RELU>
__global__ __launch_bounds__(256, 2) void k_convm(
    const u16* __restrict__ Xin, const u16* __restrict__ wpk,
    const float* __restrict__ bias, const float* __restrict__ gap2,
    u16* __restrict__ Xout) {
  constexpr int KSPT = CH / 32;            // 8 or 9
  constexpr int NPH = (KSPT + 1) / 2;      // 4 or 5
  __shared__ __align__(16) u16 lds[192 * 64];  // 192 px * 8 slots * 8 u16 = 24KB
  int r = blockIdx.y, strip = blockIdx.x;
  int h0 = strip * 4;
  int t = threadIdx.x, w = t >> 6, lane = t & 63;
  size_t base_u = ((size_t)r * 30 + h0) * 32 * CH;  // padded rows h0..h0+5
  int kb = lane >> 4;
  int pr = (lane & 15) >> 2, pc = lane & 3;
  f32x4 acc[4][7];
#pragma unroll
  for (int i = 0; i < 4; ++i)
#pragma unroll
    for (int p = 0; p < 7; ++p) acc[i][p] = f32x4{0.f, 0.f, 0.f, 0.f};
  const u16* wbase = wpk + ((size_t)(w * 4) * 64 + lane) * 8;
  for (int ph = 0; ph < NPH; ++ph) {
    const int ks_cnt = (KSPT - ph * 2 >= 2) ? 2 : 1;
    const int ne = ks_cnt * 4;
    if (ph) __syncthreads();
    for (int c = t; c < 192 * ne; c += 256) {
      int pix = c / ne, e = c - pix * ne;
      u32x4 v = *(const u32x4*)&Xin[base_u + (size_t)pix * CH + (ph * 8 + e) * 8];
      *(u32x4*)&lds[(pix * 8 + cslot(ne, e, pix)) * 8] = v;
    }
    __syncthreads();
    for (int kq = 0; kq < 9; ++kq) {
      int dh = kq / 3, dw = kq % 3;
      int pixq = (pr + dh) * 32 + pc + dw;
      for (int ks = 0; ks < ks_cnt; ++ks) {
        int kk = kq * KSPT + ph * 2 + ks;
        short8 A[4];
#pragma unroll
        for (int i = 0; i < 4; ++i)
          A[i] = *(const short8*)(wbase + (size_t)(kk * 16 + i) * 512);
        int e = ks * 4 + kb;
#pragma unroll
        for (int p = 0; p < 7; ++p) {
          int lp = pixq + 4 * p;
          short8 B = *(const short8*)&lds[(lp * 8 + cslot(ne, e, lp)) * 8];
#pragma unroll
          for (int i = 0; i < 4; ++i)
            acc[i][p] =
                __builtin_amdgcn_mfma_f32_16x16x32_bf16(A[i], B, acc[i][p], 0, 0, 0);
        }
      }
    }
  }
  // epilogue: D row = kb*4+reg (oc), col = lane&15 (pixel)
#pragma unroll
  for (int i = 0; i < 4; ++i) {
    int oc = (w * 4 + i) * 16 + kb * 4;
    f32x4 bb = *(const f32x4*)&bias[oc];
    if (IS1) bb += *(const f32x4*)&gap2[r * 256 + oc];
#pragma unroll
    for (int p = 0; p < 7; ++p) {
      f32x4 v = acc[i][p] + bb;
      if (RELU) {
        v.x = fmaxf(v.x, 0.f); v.y = fmaxf(v.y, 0.f);
        v.z = fmaxf(v.z, 0.f); v.w = fmaxf(v.w, 0.f);
      }
      __align__(8) u16 o[4] = {f2bf(v.x), f2bf(v.y), f2bf(v.z), f2bf(v.w)};
      int orow = h0 + pr + 1, ocol = 4 * p + pc + 1;
      *(u32x2*)&Xout[(((size_t)r * 30 + orow) * 32 + ocol) * 256 + oc] = *(u32x2*)o;
    }
  }
}

// ---------------- MFMA deconv(2x2,s2) + relu + 1x1 logits ----------------
__global__ __launch_bounds__(256, 2) void k_deconvm(
    const u16* __restrict__ X, const u16* __restrict__ wpkd,
    const float* __restrict__ db, const float* __restrict__ lw,
    const float* __restrict__ lb, float* __restrict__ out) {
  __shared__ __align__(16) u16 lds[112 * 256];
  __shared__ float plog[4][112];
  int r = blockIdx.y, strip = blockIdx.x, h0 = strip * 4;
  int t = threadIdx.x, w = t >> 6, lane = t & 63;
  for (int c = t; c < 112 * 32; c += 256) {
    int ip = c >> 5, e = c & 31;
    int hh = ip / 28, ww = ip % 28;
    u32x4 v = *(const u32x4*)&X[(((size_t)r * 30 + h0 + hh + 1) * 32 + ww + 1) * 256 + e * 8];
    *(u32x4*)&lds[(ip * 32 + (e ^ swz_of(ip))) * 8] = v;
  }
  __syncthreads();
  int kb = lane >> 4, colp = lane & 15;
  float lbv = lb[0];
  f32x4 lw4[4], db4[4];
#pragma unroll
  for (int i = 0; i < 4; ++i) {
    int oc = (w * 4 + i) * 16 + kb * 4;
    lw4[i] = *(const f32x4*)&lw[oc];
    db4[i] = *(const f32x4*)&db[oc];
  }
  const u16* wbase = wpkd + ((size_t)(w * 4) * 64 + lane) * 8;
  for (int kl = 0; kl < 4; ++kl) {
    f32x4 acc[4][7];
#pragma unroll
    for (int i = 0; i < 4; ++i)
#pragma unroll
      for (int p = 0; p < 7; ++p) acc[i][p] = f32x4{0.f, 0.f, 0.f, 0.f};
    for (int ks = 0; ks < 8; ++ks) {
      int kk = kl * 8 + ks;
      short8 A[4];
#pragma unroll
      for (int i = 0; i < 4; ++i)
        A[i] = *(const short8*)(wbase + (size_t)(kk * 16 + i) * 512);
      int e = ks * 4 + kb;
#pragma unroll
      for (int p = 0; p < 7; ++p) {
        int ip = p * 16 + colp;
        short8 B = *(const short8*)&lds[((ip << 5) + (e ^ swz_of(ip))) * 8];
#pragma unroll
        for (int i = 0; i < 4; ++i)
          acc[i][p] =
              __builtin_amdgcn_mfma_f32_16x16x32_bf16(A[i], B, acc[i][p], 0, 0, 0);
      }
    }
#pragma unroll
    for (int p = 0; p < 7; ++p) {
      float s = 0.f;
#pragma unroll
      for (int i = 0; i < 4; ++i) {
        f32x4 v = acc[i][p] + db4[i];
        s += lw4[i].x * fmaxf(v.x, 0.f) + lw4[i].y * fmaxf(v.y, 0.f) +
             lw4[i].z * fmaxf(v.z, 0.f) + lw4[i].w * fmaxf(v.w, 0.f);
      }
      s += __shfl_xor(s, 16, 64);
      s += __shfl_xor(s, 32, 64);
      if (lane < 16) plog[w][p * 16 + lane] = s;
    }
    __syncthreads();
    if (t < 112) {
      float s = plog[0][t] + plog[1][t] + plog[2][t] + plog[3][t] + lbv;
      int hh = t / 28, ww = t % 28;
      int k = kl >> 1, l = kl & 1;
      out[(size_t)r * 3136 + (2 * (h0 + hh) + k) * 56 + 2 * ww + l] = s;
    }
    __syncthreads();
  }
}

// ---------------- launcher ----------------
extern "C" void kernel_launch(void* const* d_in, const int* in_sizes, int n_in,
                              void* d_out, int out_size, void* d_ws, size_t ws_size,
                              hipStream_t stream) {
  const float* feat_a = (const float*)d_in[0];
  const float* mask_a = (const float*)d_in[1];
  const float* feat_b = (const float*)d_in[2];
  const float* mask_b = (const float*)d_in[3];
  const float* pos_mu = (const float*)d_in[4];
  const float* neg_mu = (const float*)d_in[5];
  const float* conv1_w = (const float*)d_in[6];
  const float* conv1_b = (const float*)d_in[7];
  const float* conv2_w = (const float*)d_in[8];
  const float* conv2_b = (const float*)d_in[9];
  const float* convs_w = (const float*)d_in[10];
  const float* convs_b = (const float*)d_in[11];
  const float* deconv_w = (const float*)d_in[12];
  const float* deconv_b = (const float*)d_in[13];
  const float* logits_w = (const float*)d_in[14];
  const float* logits_b = (const float*)d_in[15];
  float* out = (float*)d_out;

  char* P = (char*)d_ws;
  auto alloc = [&](size_t bytes) {
    char* q = P;
    P += (bytes + 255) & ~(size_t)255;
    return q;
  };
  float* m_a28 = (float*)alloc(401408 * 4);
  float* m_b28 = (float*)alloc(401408 * 4);
  float* ma_sum = (float*)alloc(512);
  float* gap = (float*)alloc(131072 * 4);
  float* gap2 = (float*)alloc(131072 * 4);
  float* pos_z = (float*)alloc(401408 * 4);
  float* neg_z = (float*)alloc(401408 * 4);
  float* w2t = (float*)alloc(65536 * 4);
  float* mu = (float*)alloc(262144 * 4);
  float* mn_part = (float*)alloc((size_t)128 * 28 * 256 * 8 * 4);
  float* ps_part = (float*)alloc(128 * 28 * 8 * 4);
  u16* wpk1 = (u16*)alloc(663552 * 2);
  u16* wpk3 = (u16*)alloc(1769472 * 2);
  u16* wpkd = (u16*)alloc(262144 * 2);
  u16* Xin = (u16*)alloc((size_t)128 * 30 * 32 * 288 * 2);
  u16* A1 = (u16*)alloc((size_t)128 * 30 * 32 * 256 * 2);
  u16* A2 = (u16*)alloc((size_t)128 * 30 * 32 * 256 * 2);

  k_pack1<<<2592, 256, 0, stream>>>(conv1_w, wpk1);
  k_pack3<<<6912, 256, 0, stream>>>(convs_w, wpk3);
  k_packd<<<1024, 256, 0, stream>>>(deconv_w, wpkd);
  k_tw_conv2<<<256, 256, 0, stream>>>(conv2_w, w2t);
  k_halo<288><<<3168, 256, 0, stream>>>(Xin);
  k_halo<256><<<2816, 256, 0, stream>>>(A1);
  k_halo<256><<<2816, 256, 0, stream>>>(A2);

  k_resize<<<dim3(128, 2), 256, 0, stream>>>(mask_a, mask_b, m_a28, m_b28, ma_sum);
  k_gap<<<dim3(64, 128), 256, 0, stream>>>(feat_a, m_a28, ma_sum, gap);
  k_gap2<<<128, 256, 0, stream>>>(gap, w2t, conv2_b, gap2);

  k_em_init<<<128, 256, 0, stream>>>(pos_mu, neg_mu, mu);
  for (int phase = 0; phase < 2; ++phase) {
    const float* x = phase ? feat_b : feat_a;
    const float* mm = phase ? m_b28 : m_a28;
    for (int s = 0; s < 6; ++s) {
      k_em_F<<<dim3(28, 128), 256, 0, stream>>>(x, mm, mu, mn_part, ps_part);
      k_em_R<<<128, 256, 0, stream>>>(mn_part, ps_part, mu);
    }
  }
  k_em_prop<<<dim3(4, 128), 256, 0, stream>>>(feat_b, mu, pos_z, neg_z);

  k_mkxin<<<dim3(14, 9, 128), 256, 0, stream>>>(feat_b, pos_z, neg_z, m_a28, Xin);

  k_convm<288, true, false><<<dim3(7, 128), 256, 0, stream>>>(
      Xin, wpk1, conv1_b, gap2, A1);
  k_convm<256, false, true><<<dim3(7, 128), 256, 0, stream>>>(
      A1, wpk3, convs_b, nullptr, A2);
  k_convm<256, false, true><<<dim3(7, 128), 256, 0, stream>>>(
      A2, wpk3 + 589824, convs_b + 256, nullptr, A1);
  k_convm<256, false, true><<<dim3(7, 128), 256, 0, stream>>>(
      A1, wpk3 + 2 * 589824, convs_b + 512, nullptr, A2);

  k_deconvm<<<dim3(7, 128), 256, 0, stream>>>(A2, wpkd, deconv_b, logits_w,
                                              logits_b, out);
}

// Round 13
// 1319.356 us; speedup vs baseline: 1.0800x; 1.0764x over previous
//
#include <hip/hip_runtime.h>
#include <cstddef>

typedef unsigned short u16;
typedef unsigned int u32;
typedef __attribute__((ext_vector_type(8))) short short8;
typedef __attribute__((ext_vector_type(4))) float f32x4;
typedef __attribute__((ext_vector_type(4))) u32 u32x4;
typedef __attribute__((ext_vector_type(2))) u32 u32x2;

__device__ inline u16 f2bf(float x) {
  union { float f; u32 u; } v; v.f = x;
  u32 r = v.u + 0x7fffu + ((v.u >> 16) & 1u);
  return (u16)(r >> 16);
}
__device__ inline int swz_of(int pix) {
  return (((pix >> 5) & 1) << 2) ^ (pix & 7);
}
__device__ inline int slot4(int e, int pix) {
  return (e ^ (pix & 3)) | ((((pix >> 2) ^ (pix >> 5)) & 1) << 2);
}

// ---------------- weight packing (MFMA A-fragment order, bf16) ----------------
__global__ void k_pack1(const float* __restrict__ w, u16* __restrict__ wpk) {
  int i = blockIdx.x * 256 + threadIdx.x;  // 81*16*512
  if (i >= 663552) return;
  int j = i & 7, l = (i >> 3) & 63, ot = (i >> 9) & 15, kk = i >> 13;
  int kq = kk / 9, ks = kk % 9;
  int ic = ks * 32 + (l >> 4) * 8 + j;
  int oc = ot * 16 + (l & 15);
  float v = (ic < 259) ? w[(oc * 259 + ic) * 9 + kq] : 0.f;
  wpk[i] = f2bf(v);
}
__global__ void k_pack3(const float* __restrict__ w, u16* __restrict__ wpk) {
  int i = blockIdx.x * 256 + threadIdx.x;  // 3*72*16*512
  if (i >= 1769472) return;
  int j = i & 7, l = (i >> 3) & 63, ot = (i >> 9) & 15, kk2 = i >> 13;
  int ll = kk2 / 72, kk = kk2 % 72;
  int kq = kk / 8, ks = kk % 8;
  int ic = ks * 32 + (l >> 4) * 8 + j;
  int oc = ot * 16 + (l & 15);
  wpk[i] = f2bf(w[((ll * 256 + oc) * 256 + ic) * 9 + kq]);
}
__global__ void k_packd(const float* __restrict__ w, u16* __restrict__ wpk) {
  int i = blockIdx.x * 256 + threadIdx.x;  // 32*16*512
  if (i >= 262144) return;
  int j = i & 7, l = (i >> 3) & 63, ot = (i >> 9) & 15, kk = i >> 13;
  int kl = kk / 8, ks = kk % 8;
  int ic = ks * 32 + (l >> 4) * 8 + j;
  int oc = ot * 16 + (l & 15);
  wpk[i] = f2bf(w[(ic * 256 + oc) * 4 + kl]);
}
__global__ void k_tw_conv2(const float* __restrict__ w, float* __restrict__ wt) {
  int i = blockIdx.x * 256 + threadIdx.x;
  if (i >= 256 * 256) return;
  int oc = i & 255, ic = i >> 8;
  wt[i] = w[oc * 256 + ic];
}

// ---------------- zero halos of NHWC-padded bf16 activation buffers ----------
template <int CH>
__global__ void k_halo(u16* __restrict__ X) {
  int i = blockIdx.x * 256 + threadIdx.x;
  const int CHB = CH / 8;
  if (i >= 128 * 176 * CHB) return;
  int e = i % CHB, q = i / CHB;
  int r = q / 176, p = q % 176;
  int row, col;
  if (p < 64) { row = (p >> 5) * 29; col = p & 31; }
  else { int q2 = p - 64; row = 1 + (q2 >> 2); int cc = q2 & 3; col = cc ? (28 + cc) : 0; }
  u32x4 z = {0, 0, 0, 0};
  *(u32x4*)&X[(((size_t)r * 30 + row) * 32 + col) * CH + e * 8] = z;
}

// ---------------- bilinear resize 56->28 ----------------
__device__ inline int resize_taps(int i, int* rows, float* wts) {
  if (i == 0) {
    rows[0] = 0; rows[1] = 1; rows[2] = 2;
    wts[0] = 3.f / 7.f; wts[1] = 3.f / 7.f; wts[2] = 1.f / 7.f; return 3;
  }
  if (i == 27) {
    rows[0] = 53; rows[1] = 54; rows[2] = 55;
    wts[0] = 1.f / 7.f; wts[1] = 3.f / 7.f; wts[2] = 3.f / 7.f; return 3;
  }
  rows[0] = 2 * i - 1; rows[1] = 2 * i; rows[2] = 2 * i + 1; rows[3] = 2 * i + 2;
  wts[0] = 0.125f; wts[1] = 0.375f; wts[2] = 0.375f; wts[3] = 0.125f; return 4;
}

__global__ __launch_bounds__(256) void k_resize(
    const float* __restrict__ ma_in, const float* __restrict__ mb_in,
    float* __restrict__ m_a28, float* __restrict__ m_b28,
    float* __restrict__ ma_sum) {
  int r = blockIdx.x, side = blockIdx.y, t = threadIdx.x;
  const float* in = (side ? mb_in : ma_in) + (size_t)r * 3136;
  float* out = (side ? m_b28 : m_a28) + (size_t)r * 784;
  float cnt = 0.f;
  for (int p = t; p < 784; p += 256) {
    int i = p / 28, j = p % 28;
    int rr_[4], cc_[4]; float wr[4], wc[4];
    int nr = resize_taps(i, rr_, wr), nc = resize_taps(j, cc_, wc);
    float v = 0.f;
    for (int a = 0; a < nr; ++a) {
      float rv = 0.f;
      for (int b = 0; b < nc; ++b) rv += wc[b] * in[rr_[a] * 56 + cc_[b]];
      v += wr[a] * rv;
    }
    out[p] = v;
    cnt += (v >= 0.f) ? 1.f : 0.f;
  }
  __shared__ float red[4];
  for (int off = 32; off; off >>= 1) cnt += __shfl_xor(cnt, off, 64);
  int lane = t & 63, wid = t >> 6;
  if (lane == 0) red[wid] = cnt;
  __syncthreads();
  if (t == 0 && side == 0) ma_sum[r] = red[0] + red[1] + red[2] + red[3];
}

// ---------------- gap + conv2(gap) ----------------
__global__ __launch_bounds__(256) void k_gap(
    const float* __restrict__ feat_a, const float* __restrict__ m_a28,
    const float* __restrict__ ma_sum, float* __restrict__ gap) {
  int r = blockIdx.y, wid = threadIdx.x >> 6, lane = threadIdx.x & 63;
  int c = blockIdx.x * 4 + wid;
  const float* x = feat_a + ((size_t)r * 256 + c) * 784;
  const float* m = m_a28 + (size_t)r * 784;
  float s = 0.f;
  for (int n = lane; n < 784; n += 64)
    s += x[n] * ((m[n] >= 0.f) ? 1.f : 0.f);
  for (int off = 32; off; off >>= 1) s += __shfl_xor(s, off, 64);
  if (lane == 0) gap[r * 256 + c] = s / (ma_sum[r] + 1e-5f);
}

__global__ __launch_bounds__(256) void k_gap2(
    const float* __restrict__ gap, const float* __restrict__ w2t,
    const float* __restrict__ b2, float* __restrict__ gap2) {
  int r = blockIdx.x, t = threadIdx.x;
  __shared__ float g[256];
  g[t] = gap[r * 256 + t];
  __syncthreads();
  float acc = b2[t];
  for (int ic = 0; ic < 256; ++ic) acc += w2t[ic * 256 + t] * g[ic];
  gap2[r * 256 + t] = acc;
}

// ---------------- EM ----------------
__global__ __launch_bounds__(256) void k_em_init(
    const float* __restrict__ pos_mu, const float* __restrict__ neg_mu,
    float* __restrict__ mu) {
  int r = blockIdx.x, t = threadIdx.x;
  float* o = mu + (size_t)r * 2048 + t * 8;
#pragma unroll
  for (int k = 0; k < 4; ++k) {
    o[k] = pos_mu[t * 4 + k];
    o[k + 4] = neg_mu[t * 4 + k];
  }
}

// fused stage: 49-px tile; x staged once in LDS; z-step + partial munew + z-sums
__global__ __launch_bounds__(256) void k_em_F(
    const float* __restrict__ x, const float* __restrict__ mres,
    const float* __restrict__ mu, float* __restrict__ mn_part,
    float* __restrict__ ps_part) {
  __shared__ float xs[256][53];             // 54.3 KB, odd pad -> conflict-free
  __shared__ float Sp[4][49][8];            // partial S; Sp[0] reused as z
  __shared__ __align__(16) float muL[256][8];
  int tile = blockIdx.x, r = blockIdx.y, t = threadIdx.x;
  int n0 = tile * 49;
  {
    const f32x4* src = (const f32x4*)(mu + (size_t)r * 2048);
    f32x4 a = src[t * 2], b = src[t * 2 + 1];
    *(f32x4*)&muL[t][0] = a; *(f32x4*)&muL[t][4] = b;
  }
  const float* xb = x + (size_t)r * 200704 + n0;
  for (int i = t; i < 12544; i += 256) {
    int c = i / 49, j = i - c * 49;
    xs[c][j] = xb[c * 784 + j];
  }
  __syncthreads();
  // pass A: 4 c-groups x 49 px
  if (t < 196) {
    int g = t / 49, n = t - g * 49;
    float S[8] = {0, 0, 0, 0, 0, 0, 0, 0};
#pragma unroll 8
    for (int cc = 0; cc < 64; ++cc) {
      int c = g * 64 + cc;
      float xv = xs[c][n];
      f32x4 a = *(const f32x4*)&muL[c][0];
      f32x4 b = *(const f32x4*)&muL[c][4];
      S[0] += xv * a.x; S[1] += xv * a.y; S[2] += xv * a.z; S[3] += xv * a.w;
      S[4] += xv * b.x; S[5] += xv * b.y; S[6] += xv * b.z; S[7] += xv * b.w;
    }
#pragma unroll
    for (int k = 0; k < 8; ++k) Sp[g][n][k] = S[k];
  }
  __syncthreads();
  if (t < 49) {
    float S[8];
#pragma unroll
    for (int k = 0; k < 8; ++k)
      S[k] = Sp[0][t][k] + Sp[1][t][k] + Sp[2][t][k] + Sp[3][t][k];
    float m = (mres[(size_t)r * 784 + n0 + t] >= 0.f) ? 1.f : 0.f;
    float mxp = fmaxf(fmaxf(S[0], S[1]), fmaxf(S[2], S[3]));
    float e0 = expf(20.f * (S[0] - mxp)), e1 = expf(20.f * (S[1] - mxp));
    float e2 = expf(20.f * (S[2] - mxp)), e3 = expf(20.f * (S[3] - mxp));
    float dp = m / (e0 + e1 + e2 + e3);
    float mxn = fmaxf(fmaxf(S[4], S[5]), fmaxf(S[6], S[7]));
    float f0 = expf(20.f * (S[4] - mxn)), f1 = expf(20.f * (S[5] - mxn));
    float f2 = expf(20.f * (S[6] - mxn)), f3 = expf(20.f * (S[7] - mxn));
    float dn = (1.f - m) / (f0 + f1 + f2 + f3);
    Sp[0][t][0] = e0 * dp; Sp[0][t][1] = e1 * dp;
    Sp[0][t][2] = e2 * dp; Sp[0][t][3] = e3 * dp;
    Sp[0][t][4] = f0 * dn; Sp[0][t][5] = f1 * dn;
    Sp[0][t][6] = f2 * dn; Sp[0][t][7] = f3 * dn;
  }
  __syncthreads();
  if (t < 8) {
    float s = 0.f;
    for (int n = 0; n < 49; ++n) s += Sp[0][n][t];
    ps_part[((size_t)r * 16 + tile) * 8 + t] = s;
  }
  // pass B: thread t = channel c
  float acc[8] = {0, 0, 0, 0, 0, 0, 0, 0};
  for (int n = 0; n < 49; ++n) {
    float xv = xs[t][n];
    f32x4 z0 = *(const f32x4*)&Sp[0][n][0];
    f32x4 z1 = *(const f32x4*)&Sp[0][n][4];
    acc[0] += xv * z0.x; acc[1] += xv * z0.y; acc[2] += xv * z0.z; acc[3] += xv * z0.w;
    acc[4] += xv * z1.x; acc[5] += xv * z1.y; acc[6] += xv * z1.z; acc[7] += xv * z1.w;
  }
  float* o = mn_part + (((size_t)r * 16 + tile) * 256 + t) * 8;
  *(f32x4*)&o[0] = f32x4{acc[0], acc[1], acc[2], acc[3]};
  *(f32x4*)&o[4] = f32x4{acc[4], acc[5], acc[6], acc[7]};
}

// reduce: sum 16 partials, exact l1+l2 fold, write mu
__global__ __launch_bounds__(256) void k_em_R(
    const float* __restrict__ mn_part, const float* __restrict__ ps_part,
    float* __restrict__ mu) {
  __shared__ float redsh[4][8];
  __shared__ float csv[8];
  __shared__ float inv[8];
  int r = blockIdx.x, t = threadIdx.x, lane = t & 63, wid = t >> 6;
  float mn[8] = {0, 0, 0, 0, 0, 0, 0, 0};
#pragma unroll
  for (int tile = 0; tile < 16; ++tile) {
    const float* p = mn_part + (((size_t)r * 16 + tile) * 256 + t) * 8;
    f32x4 a = *(const f32x4*)&p[0];
    f32x4 b = *(const f32x4*)&p[4];
    mn[0] += a.x; mn[1] += a.y; mn[2] += a.z; mn[3] += a.w;
    mn[4] += b.x; mn[5] += b.y; mn[6] += b.z; mn[7] += b.w;
  }
  if (t < 8) {
    float s = 0.f;
#pragma unroll
    for (int tile = 0; tile < 16; ++tile)
      s += ps_part[((size_t)r * 16 + tile) * 8 + t];
    csv[t] = s;
  }
  float sq[8];
#pragma unroll
  for (int k = 0; k < 8; ++k) sq[k] = mn[k] * mn[k];
#pragma unroll
  for (int k = 0; k < 8; ++k)
    for (int off = 32; off; off >>= 1) sq[k] += __shfl_xor(sq[k], off, 64);
  if (lane == 0) {
#pragma unroll
    for (int k = 0; k < 8; ++k) redsh[wid][k] = sq[k];
  }
  __syncthreads();
  if (t < 8) {
    float rn = redsh[0][t] + redsh[1][t] + redsh[2][t] + redsh[3][t];
    float s = 1.f / (1e-6f + csv[t]);
    inv[t] = s / (1e-6f + s * sqrtf(rn));
  }
  __syncthreads();
  float* o = mu + (size_t)r * 2048 + t * 8;
  *(f32x4*)&o[0] = f32x4{mn[0] * inv[0], mn[1] * inv[1], mn[2] * inv[2], mn[3] * inv[3]};
  *(f32x4*)&o[4] = f32x4{mn[4] * inv[4], mn[5] * inv[5], mn[6] * inv[6], mn[7] * inv[7]};
}

__global__ __launch_bounds__(256) void k_em_prop(
    const float* __restrict__ xb, const float* __restrict__ mu,
    float* __restrict__ pos_z, float* __restrict__ neg_z) {
  __shared__ __align__(16) float muL[256][8];
  int r = blockIdx.y, t = threadIdx.x;
  {
    const f32x4* src = (const f32x4*)(mu + (size_t)r * 2048);
    f32x4 a = src[t * 2], b = src[t * 2 + 1];
    *(f32x4*)&muL[t][0] = a; *(f32x4*)&muL[t][4] = b;
  }
  __syncthreads();
  if (t >= 196) return;
  int n = blockIdx.x * 196 + t;
  const float* xp = xb + (size_t)r * 200704 + n;
  float S[8] = {0, 0, 0, 0, 0, 0, 0, 0};
#pragma unroll 8
  for (int c = 0; c < 256; ++c) {
    float xv = xp[c * 784];
    f32x4 a = *(const f32x4*)&muL[c][0];
    f32x4 b = *(const f32x4*)&muL[c][4];
    S[0] += xv * a.x; S[1] += xv * a.y; S[2] += xv * a.z; S[3] += xv * a.w;
    S[4] += xv * b.x; S[5] += xv * b.y; S[6] += xv * b.z; S[7] += xv * b.w;
  }
  float mx = S[0];
#pragma unroll
  for (int k = 1; k < 8; ++k) mx = fmaxf(mx, S[k]);
  float e[8], d = 0.f;
#pragma unroll
  for (int k = 0; k < 8; ++k) { e[k] = expf(S[k] - mx); d += e[k]; }
  float invd = 1.f / d;
  pos_z[(size_t)r * 784 + n] = (e[0] + e[1] + e[2] + e[3]) * invd;
  neg_z[(size_t)r * 784 + n] = (e[4] + e[5] + e[6] + e[7]) * invd;
}

// ---------------- build conv1 input: NHWC-padded bf16 [r][30][32][288] ------
__global__ __launch_bounds__(256) void k_mkxin(
    const float* __restrict__ feat_b, const float* __restrict__ pos_z,
    const float* __restrict__ neg_z, const float* __restrict__ m_a28,
    u16* __restrict__ Xin) {
  __shared__ u16 tile[32][65];
  int pt = blockIdx.x, cb = blockIdx.y, r = blockIdx.z;
  int t = threadIdx.x, w = t >> 6, lane = t & 63;
  int p0 = pt * 56;
#pragma unroll
  for (int i2 = 0; i2 < 8; ++i2) {
    int cl = w * 8 + i2;
    float v = 0.f;
    if (lane < 56) {
      int n = p0 + lane;
      if (cb < 8) v = feat_b[((size_t)r * 256 + cb * 32 + cl) * 784 + n];
      else if (cl == 0) v = pos_z[(size_t)r * 784 + n];
      else if (cl == 1) v = neg_z[(size_t)r * 784 + n];
      else if (cl == 2) v = m_a28[(size_t)r * 784 + n];
    }
    tile[cl][lane] = f2bf(v);
  }
  __syncthreads();
  int pl = t >> 2, eo = t & 3;
  if (pl < 56) {
    int n = p0 + pl, row = n / 28 + 1, col = n % 28 + 1;
    __align__(16) u16 o[8];
#pragma unroll
    for (int j2 = 0; j2 < 8; ++j2) o[j2] = tile[eo * 8 + j2][pl];
    *(u32x4*)&Xin[(((size_t)r * 30 + row) * 32 + col) * 288 + cb * 32 + eo * 8] =
        *(u32x4*)o;
  }
}

// ---- MFMA 3x3 conv: implicit GEMM, 4-row strips, T14 async-STAGE split -----
template <int CH, bool IS1, bool RELU>
__global__ __launch_bounds__(256, 2) void k_convm(
    const u16* __restrict__ Xin, const u16* __restrict__ wpk,
    const float* __restrict__ bias, const float* __restrict__ gap2,
    u16* __restrict__ Xout) {
  constexpr int KSPT = CH / 32;            // 8 or 9
  constexpr int NFULL = KSPT / 2;          // 4 full phases (ks=2, ne=8)
  constexpr bool TAIL = (KSPT & 1) != 0;   // CH==288 extra ks=1 phase
  __shared__ __align__(16) u16 lds[192 * 64];  // 24KB
  int r = blockIdx.y, strip = blockIdx.x;
  int h0 = strip * 4;
  int t = threadIdx.x, w = t >> 6, lane = t & 63;
  size_t base_u = ((size_t)r * 30 + h0) * 32 * CH;
  int kb = lane >> 4;
  int pr = (lane & 15) >> 2, pc = lane & 3;
  f32x4 acc[4][7];
#pragma unroll
  for (int i = 0; i < 4; ++i)
#pragma unroll
    for (int p = 0; p < 7; ++p) acc[i][p] = f32x4{0.f, 0.f, 0.f, 0.f};
  const u16* wbase = wpk + ((size_t)(w * 4) * 64 + lane) * 8;
  // prefetch phase 0 into registers
  u32x4 pf[6];
#pragma unroll
  for (int c0 = 0; c0 < 6; ++c0) {
    int c = c0 * 256 + t, pix = c >> 3, e = c & 7;
    pf[c0] = *(const u32x4*)&Xin[base_u + (size_t)pix * CH + e * 8];
  }
  for (int ph = 0; ph < NFULL; ++ph) {
    if (ph) __syncthreads();
    // write current phase from registers (swizzled)
#pragma unroll
    for (int c0 = 0; c0 < 6; ++c0) {
      int c = c0 * 256 + t, pix = c >> 3, e = c & 7;
      *(u32x4*)&lds[(pix * 8 + (e ^ swz_of(pix))) * 8] = pf[c0];
    }
    __syncthreads();
    // issue next phase's loads; latency hides under this phase's MFMAs
    if (ph + 1 < NFULL) {
#pragma unroll
      for (int c0 = 0; c0 < 6; ++c0) {
        int c = c0 * 256 + t, pix = c >> 3, e = c & 7;
        pf[c0] = *(const u32x4*)&Xin[base_u + (size_t)pix * CH +
                                     ((size_t)(ph + 1) * 8 + e) * 8];
      }
    } else if (TAIL) {
#pragma unroll
      for (int c0 = 0; c0 < 3; ++c0) {
        int c = c0 * 256 + t, pix = c >> 2, e = c & 3;
        pf[c0] = *(const u32x4*)&Xin[base_u + (size_t)pix * CH +
                                     ((size_t)(KSPT - 1) * 4 + e) * 8];
      }
    }
    for (int kq = 0; kq < 9; ++kq) {
      int dh = kq / 3, dw = kq % 3;
      int pixq = (pr + dh) * 32 + pc + dw;
      for (int ks = 0; ks < 2; ++ks) {
        int kk = kq * KSPT + ph * 2 + ks;
        short8 A[4];
#pragma unroll
        for (int i = 0; i < 4; ++i)
          A[i] = *(const short8*)(wbase + (size_t)(kk * 16 + i) * 512);
        int e = ks * 4 + kb;
#pragma unroll
        for (int p = 0; p < 7; ++p) {
          int lp = pixq + 4 * p;
          short8 B = *(const short8*)&lds[(lp * 8 + (e ^ swz_of(lp))) * 8];
#pragma unroll
          for (int i = 0; i < 4; ++i)
            acc[i][p] =
                __builtin_amdgcn_mfma_f32_16x16x32_bf16(A[i], B, acc[i][p], 0, 0, 0);
        }
      }
    }
  }
  if constexpr (TAIL) {
    __syncthreads();
#pragma unroll
    for (int c0 = 0; c0 < 3; ++c0) {
      int c = c0 * 256 + t, pix = c >> 2, e = c & 3;
      *(u32x4*)&lds[(pix * 8 + slot4(e, pix)) * 8] = pf[c0];
    }
    __syncthreads();
    for (int kq = 0; kq < 9; ++kq) {
      int dh = kq / 3, dw = kq % 3;
      int pixq = (pr + dh) * 32 + pc + dw;
      int kk = kq * KSPT + KSPT - 1;
      short8 A[4];
#pragma unroll
      for (int i = 0; i < 4; ++i)
        A[i] = *(const short8*)(wbase + (size_t)(kk * 16 + i) * 512);
#pragma unroll
      for (int p = 0; p < 7; ++p) {
        int lp = pixq + 4 * p;
        short8 B = *(const short8*)&lds[(lp * 8 + slot4(kb, lp)) * 8];
#pragma unroll
        for (int i = 0; i < 4; ++i)
          acc[i][p] =
              __builtin_amdgcn_mfma_f32_16x16x32_bf16(A[i], B, acc[i][p], 0, 0, 0);
      }
    }
  }
  // epilogue: D row = kb*4+reg (oc), col = lane&15 (pixel)
#pragma unroll
  for (int i = 0; i < 4; ++i) {
    int oc = (w * 4 + i) * 16 + kb * 4;
    f32x4 bb = *(const f32x4*)&bias[oc];
    if (IS1) bb += *(const f32x4*)&gap2[r * 256 + oc];
#pragma unroll
    for (int p = 0; p < 7; ++p) {
      f32x4 v = acc[i][p] + bb;
      if (RELU) {
        v.x = fmaxf(v.x, 0.f); v.y = fmaxf(v.y, 0.f);
        v.z = fmaxf(v.z, 0.f); v.w = fmaxf(v.w, 0.f);
      }
      __align__(8) u16 o[4] = {f2bf(v.x), f2bf(v.y), f2bf(v.z), f2bf(v.w)};
      int orow = h0 + pr + 1, ocol = 4 * p + pc + 1;
      *(u32x2*)&Xout[(((size_t)r * 30 + orow) * 32 + ocol) * 256 + oc] = *(u32x2*)o;
    }
  }
}

// ---------------- MFMA deconv(2x2,s2) + relu + 1x1 logits ----------------
__global__ __launch_bounds__(256, 2) void k_deconvm(
    const u16* __restrict__ X, const u16* __restrict__ wpkd,
    const float* __restrict__ db, const float* __restrict__ lw,
    const float* __restrict__ lb, float* __restrict__ out) {
  __shared__ __align__(16) u16 lds[112 * 256];
  __shared__ float plog[4][112];
  int r = blockIdx.y, strip = blockIdx.x, h0 = strip * 4;
  int t = threadIdx.x, w = t >> 6, lane = t & 63;
  for (int c = t; c < 112 * 32; c += 256) {
    int ip = c >> 5, e = c & 31;
    int hh = ip / 28, ww = ip % 28;
    u32x4 v = *(const u32x4*)&X[(((size_t)r * 30 + h0 + hh + 1) * 32 + ww + 1) * 256 + e * 8];
    *(u32x4*)&lds[(ip * 32 + (e ^ swz_of(ip))) * 8] = v;
  }
  __syncthreads();
  int kb = lane >> 4, colp = lane & 15;
  float lbv = lb[0];
  f32x4 lw4[4], db4[4];
#pragma unroll
  for (int i = 0; i < 4; ++i) {
    int oc = (w * 4 + i) * 16 + kb * 4;
    lw4[i] = *(const f32x4*)&lw[oc];
    db4[i] = *(const f32x4*)&db[oc];
  }
  const u16* wbase = wpkd + ((size_t)(w * 4) * 64 + lane) * 8;
  for (int kl = 0; kl < 4; ++kl) {
    f32x4 acc[4][7];
#pragma unroll
    for (int i = 0; i < 4; ++i)
#pragma unroll
      for (int p = 0; p < 7; ++p) acc[i][p] = f32x4{0.f, 0.f, 0.f, 0.f};
    for (int ks = 0; ks < 8; ++ks) {
      int kk = kl * 8 + ks;
      short8 A[4];
#pragma unroll
      for (int i = 0; i < 4; ++i)
        A[i] = *(const short8*)(wbase + (size_t)(kk * 16 + i) * 512);
      int e = ks * 4 + kb;
#pragma unroll
      for (int p = 0; p < 7; ++p) {
        int ip = p * 16 + colp;
        short8 B = *(const short8*)&lds[((ip << 5) + (e ^ swz_of(ip))) * 8];
#pragma unroll
        for (int i = 0; i < 4; ++i)
          acc[i][p] =
              __builtin_amdgcn_mfma_f32_16x16x32_bf16(A[i], B, acc[i][p], 0, 0, 0);
      }
    }
#pragma unroll
    for (int p = 0; p < 7; ++p) {
      float s = 0.f;
#pragma unroll
      for (int i = 0; i < 4; ++i) {
        f32x4 v = acc[i][p] + db4[i];
        s += lw4[i].x * fmaxf(v.x, 0.f) + lw4[i].y * fmaxf(v.y, 0.f) +
             lw4[i].z * fmaxf(v.z, 0.f) + lw4[i].w * fmaxf(v.w, 0.f);
      }
      s += __shfl_xor(s, 16, 64);
      s += __shfl_xor(s, 32, 64);
      if (lane < 16) plog[w][p * 16 + lane] = s;
    }
    __syncthreads();
    if (t < 112) {
      float s = plog[0][t] + plog[1][t] + plog[2][t] + plog[3][t] + lbv;
      int hh = t / 28, ww = t % 28;
      int k = kl >> 1, l = kl & 1;
      out[(size_t)r * 3136 + (2 * (h0 + hh) + k) * 56 + 2 * ww + l] = s;
    }
    __syncthreads();
  }
}

// ---------------- launcher ----------------
extern "C" void kernel_launch(void* const* d_in, const int* in_sizes, int n_in,
                              void* d_out, int out_size, void* d_ws, size_t ws_size,
                              hipStream_t stream) {
  const float* feat_a = (const float*)d_in[0];
  const float* mask_a = (const float*)d_in[1];
  const float* feat_b = (const float*)d_in[2];
  const float* mask_b = (const float*)d_in[3];
  const float* pos_mu = (const float*)d_in[4];
  const float* neg_mu = (const float*)d_in[5];
  const float* conv1_w = (const float*)d_in[6];
  const float* conv1_b = (const float*)d_in[7];
  const float* conv2_w = (const float*)d_in[8];
  const float* conv2_b = (const float*)d_in[9];
  const float* convs_w = (const float*)d_in[10];
  const float* convs_b = (const float*)d_in[11];
  const float* deconv_w = (const float*)d_in[12];
  const float* deconv_b = (const float*)d_in[13];
  const float* logits_w = (const float*)d_in[14];
  const float* logits_b = (const float*)d_in[15];
  float* out = (float*)d_out;

  char* P = (char*)d_ws;
  auto alloc = [&](size_t bytes) {
    char* q = P;
    P += (bytes + 255) & ~(size_t)255;
    return q;
  };
  float* m_a28 = (float*)alloc(401408 * 4);
  float* m_b28 = (float*)alloc(401408 * 4);
  float* ma_sum = (float*)alloc(512);
  float* gap = (float*)alloc(131072 * 4);
  float* gap2 = (float*)alloc(131072 * 4);
  float* pos_z = (float*)alloc(401408 * 4);
  float* neg_z = (float*)alloc(401408 * 4);
  float* w2t = (float*)alloc(65536 * 4);
  float* mu = (float*)alloc(262144 * 4);
  float* mn_part = (float*)alloc((size_t)128 * 16 * 256 * 8 * 4);
  float* ps_part = (float*)alloc(128 * 16 * 8 * 4);
  u16* wpk1 = (u16*)alloc(663552 * 2);
  u16* wpk3 = (u16*)alloc(1769472 * 2);
  u16* wpkd = (u16*)alloc(262144 * 2);
  u16* Xin = (u16*)alloc((size_t)128 * 30 * 32 * 288 * 2);
  u16* A1 = (u16*)alloc((size_t)128 * 30 * 32 * 256 * 2);
  u16* A2 = (u16*)alloc((size_t)128 * 30 * 32 * 256 * 2);

  k_pack1<<<2592, 256, 0, stream>>>(conv1_w, wpk1);
  k_pack3<<<6912, 256, 0, stream>>>(convs_w, wpk3);
  k_packd<<<1024, 256, 0, stream>>>(deconv_w, wpkd);
  k_tw_conv2<<<256, 256, 0, stream>>>(conv2_w, w2t);
  k_halo<288><<<3168, 256, 0, stream>>>(Xin);
  k_halo<256><<<2816, 256, 0, stream>>>(A1);
  k_halo<256><<<2816, 256, 0, stream>>>(A2);

  k_resize<<<dim3(128, 2), 256, 0, stream>>>(mask_a, mask_b, m_a28, m_b28, ma_sum);
  k_gap<<<dim3(64, 128), 256, 0, stream>>>(feat_a, m_a28, ma_sum, gap);
  k_gap2<<<128, 256, 0, stream>>>(gap, w2t, conv2_b, gap2);

  k_em_init<<<128, 256, 0, stream>>>(pos_mu, neg_mu, mu);
  for (int phase = 0; phase < 2; ++phase) {
    const float* x = phase ? feat_b : feat_a;
    const float* mm = phase ? m_b28 : m_a28;
    for (int s = 0; s < 6; ++s) {
      k_em_F<<<dim3(16, 128), 256, 0, stream>>>(x, mm, mu, mn_part, ps_part);
      k_em_R<<<128, 256, 0, stream>>>(mn_part, ps_part, mu);
    }
  }
  k_em_prop<<<dim3(4, 128), 256, 0, stream>>>(feat_b, mu, pos_z, neg_z);

  k_mkxin<<<dim3(14, 9, 128), 256, 0, stream>>>(feat_b, pos_z, neg_z, m_a28, Xin);

  k_convm<288, true, false><<<dim3(7, 128), 256, 0, stream>>>(
      Xin, wpk1, conv1_b, gap2, A1);
  k_convm<256, false, true><<<dim3(7, 128), 256, 0, stream>>>(
      A1, wpk3, convs_b, nullptr, A2);
  k_convm<256, false, true><<<dim3(7, 128), 256, 0, stream>>>(
      A2, wpk3 + 589824, convs_b + 256, nullptr, A1);
  k_convm<256, false, true><<<dim3(7, 128), 256, 0, stream>>>(
      A1, wpk3 + 2 * 589824, convs_b + 512, nullptr, A2);

  k_deconvm<<<dim3(7, 128), 256, 0, stream>>>(A2, wpkd, deconv_b, logits_w,
                                              logits_b, out);
}